// Round 9
// baseline (440.170 us; speedup 1.0000x reference)
//
#include <hip/hip_runtime.h>
#include <hip/hip_fp16.h>

#define FDIM 64
#define SB 200        // scan blocks
#define P_BLK 1024    // binning blocks
#define NB_MAX 400    // max dst buckets (ceil(100000/256)=391)
#define BKT_NODES 256 // nodes per dst bucket (dst >> 8)
#define CHUNK_CAP 3200 // LDS staging capacity (chunk = ceil(E/P_BLK) = 3125)

typedef __attribute__((ext_vector_type(8))) short short8;
typedef __attribute__((ext_vector_type(4))) float float4_;

__device__ __forceinline__ unsigned short f2bf(float x) {
    unsigned u = __float_as_uint(x);
    return (unsigned short)((u + 0x7FFF + ((u >> 16) & 1)) >> 16);   // RNE
}

// ---- MFMA GEMM: XWh[r][n][f] = fp16( X[n][:] @ W[r][:][f] ) ---- (unchanged)
__global__ __launch_bounds__(256) void xw_gemm_mfma(
    const float* __restrict__ X, const float* __restrict__ Wmat,
    __half* __restrict__ XWh, int N, int R)
{
    __shared__ unsigned short Wt[4 * 64 * 72];
    const int tid  = threadIdx.x;
    const int lane = tid & 63;
    const int wave = tid >> 6;
    const int quad = lane >> 4;
    const int l15  = lane & 15;
    const int blockBase = blockIdx.x * 256;

    short8 bfrag[4][2];
    bool tvalid[4];
#pragma unroll
    for (int t = 0; t < 4; ++t) {
        const int tb = blockBase + (wave * 4 + t) * 16;
        tvalid[t] = (tb < N);
        if (tvalid[t]) {
            const float* xp = X + (size_t)(tb + l15) * FDIM + quad * 8;
            const float4 x0 = *(const float4*)(xp);
            const float4 x1 = *(const float4*)(xp + 4);
            const float4 x2 = *(const float4*)(xp + 32);
            const float4 x3 = *(const float4*)(xp + 36);
            short8 b0, b1;
            b0[0]=f2bf(x0.x); b0[1]=f2bf(x0.y); b0[2]=f2bf(x0.z); b0[3]=f2bf(x0.w);
            b0[4]=f2bf(x1.x); b0[5]=f2bf(x1.y); b0[6]=f2bf(x1.z); b0[7]=f2bf(x1.w);
            b1[0]=f2bf(x2.x); b1[1]=f2bf(x2.y); b1[2]=f2bf(x2.z); b1[3]=f2bf(x2.w);
            b1[4]=f2bf(x3.x); b1[5]=f2bf(x3.y); b1[6]=f2bf(x3.z); b1[7]=f2bf(x3.w);
            bfrag[t][0] = b0; bfrag[t][1] = b1;
        } else {
            bfrag[t][0] = (short8)(0); bfrag[t][1] = (short8)(0);
        }
    }

    for (int rp = 0; rp < 2; ++rp) {
        __syncthreads();
#pragma unroll
        for (int it = 0; it < 16; ++it) {
            const int idx = it * 256 + tid;
            const int k  = idx & 63;
            const int f4 = (idx >> 6) & 15;
            const int r  = idx >> 10;
            const float4 w = *(const float4*)(Wmat + (((size_t)(rp * 4 + r) * FDIM + k) * FDIM + f4 * 4));
            const int base = (r * 64 + f4 * 4) * 72 + k;
            Wt[base + 0 * 72] = f2bf(w.x);
            Wt[base + 1 * 72] = f2bf(w.y);
            Wt[base + 2 * 72] = f2bf(w.z);
            Wt[base + 3 * 72] = f2bf(w.w);
        }
        __syncthreads();

#pragma unroll
        for (int t = 0; t < 4; ++t) {
            if (!tvalid[t]) continue;
            const int tb = blockBase + (wave * 4 + t) * 16;
            const int node = tb + l15;
#pragma unroll
            for (int r = 0; r < 4; ++r) {
                __half* orow = XWh + ((size_t)(rp * 4 + r) * N + node) * FDIM;
#pragma unroll
                for (int ft = 0; ft < 4; ++ft) {
                    const int f = ft * 16 + l15;
                    const unsigned short* wp = &Wt[(r * 64 + f) * 72 + quad * 8];
                    const short8 a0 = *(const short8*)(wp);
                    const short8 a1 = *(const short8*)(wp + 32);
                    float4_ acc = {0.f, 0.f, 0.f, 0.f};
                    acc = __builtin_amdgcn_mfma_f32_16x16x32_bf16(a0, bfrag[t][0], acc, 0, 0, 0);
                    acc = __builtin_amdgcn_mfma_f32_16x16x32_bf16(a1, bfrag[t][1], acc, 0, 0, 0);
                    const __half2 h01 = __floats2half2_rn(acc[0], acc[1]);
                    const __half2 h23 = __floats2half2_rn(acc[2], acc[3]);
                    uint2 st;
                    st.x = *(const unsigned*)&h01;
                    st.y = *(const unsigned*)&h23;
                    *(uint2*)(orow + ft * 16 + quad * 4) = st;
                }
            }
        }
    }
}

// ---- histogram: per-block LDS bucket counts + global per-node counts ----
__global__ __launch_bounds__(256) void bin_hist(
    const int* __restrict__ dst, int* __restrict__ cnt,
    int* __restrict__ nodeCnt, int E, int B, int chunk)
{
    __shared__ int lh[NB_MAX];
    const int p = blockIdx.x, tid = threadIdx.x;
    for (int b = tid; b < B; b += 256) lh[b] = 0;
    __syncthreads();
    const int i0 = p * chunk, iend = min(i0 + chunk, E);
    for (int i = i0 + tid; i < iend; i += 256) {
        const int d = dst[i];
        atomicAdd(&lh[d >> 8], 1);
        atomicAdd(&nodeCnt[d], 1);
    }
    __syncthreads();
    for (int b = tid; b < B; b += 256) cnt[(size_t)b * P_BLK + p] = lh[b];
}

// ---- hierarchical exclusive scan (used for both offs and nodeOffs) ----
__global__ __launch_bounds__(256) void scan_partial(
    const int* __restrict__ cnt, int* __restrict__ blockSums, int M, int CH)
{
    __shared__ int sh[256];
    const int b = blockIdx.x, tid = threadIdx.x;
    const int i0 = b * CH, iend = min(i0 + CH, M);
    int s = 0;
    for (int i = i0 + tid; i < iend; i += 256) s += cnt[i];
    sh[tid] = s; __syncthreads();
    for (int off = 128; off > 0; off >>= 1) {
        if (tid < off) sh[tid] += sh[tid + off];
        __syncthreads();
    }
    if (tid == 0) blockSums[b] = sh[0];
}

__global__ __launch_bounds__(256) void scan_block(int* blockSums, int nb)
{
    __shared__ int sh[256];
    const int tid = threadIdx.x;
    const int v = (tid < nb) ? blockSums[tid] : 0;
    sh[tid] = v; __syncthreads();
    for (int off = 1; off < 256; off <<= 1) {
        const int t = (tid >= off) ? sh[tid - off] : 0;
        __syncthreads();
        sh[tid] += t;
        __syncthreads();
    }
    if (tid < nb) blockSums[tid] = sh[tid] - v;   // exclusive
}

__global__ __launch_bounds__(64) void scan_final(
    const int* __restrict__ cnt, const int* __restrict__ blockSums,
    int* __restrict__ offs, int M, int CH, int E)
{
    const int b = blockIdx.x, lane = threadIdx.x;
    const int i0 = b * CH, iend = min(i0 + CH, M);
    int carry = blockSums[b];
    for (int t = i0; t < iend; t += 64) {
        const int i = t + lane;
        const int c = (i < iend) ? cnt[i] : 0;
        int v = c;
#pragma unroll
        for (int o = 1; o < 64; o <<= 1) {
            const int u = __shfl_up(v, o, 64);
            if (lane >= o) v += u;
        }
        if (i < iend) offs[i] = carry + v - c;
        carry += __shfl(v, 63, 64);
    }
    if (b == (int)gridDim.x - 1 && lane == 0) offs[M] = E;
}

// ---- LDS-staged scatter: counting-sort the block's chunk by bucket in LDS,
// then write bucket-ordered bursts (lines written ~once). ----
// record: lo = key(20b) | dstLow(8b)<<20 ; hi = A bits
__global__ __launch_bounds__(256) void bin_scatter(
    const int* __restrict__ src, const int* __restrict__ dst,
    const int* __restrict__ etype, const float* __restrict__ A,
    const int* __restrict__ offs, int2* __restrict__ packed,
    int E, int N, int B, int chunk)
{
    __shared__ int lcnt[NB_MAX];            // counts -> cursors
    __shared__ int lpfx[NB_MAX];            // in-chunk exclusive prefix
    __shared__ int gb[NB_MAX];              // global base - lpfx
    __shared__ int2 recs[CHUNK_CAP];        // 25.6 KB staged records
    __shared__ unsigned short rbkt[CHUNK_CAP]; // 6.4 KB bucket per slot
    const int p = blockIdx.x, tid = threadIdx.x;
    const int i0 = p * chunk, iend = min(i0 + chunk, E);

    for (int b = tid; b < B; b += 256) lcnt[b] = 0;
    __syncthreads();
    for (int i = i0 + tid; i < iend; i += 256)
        atomicAdd(&lcnt[dst[i] >> 8], 1);
    __syncthreads();

    // wave-0 exclusive prefix over B buckets
    if (tid < 64) {
        int carry = 0;
        for (int t0 = 0; t0 < B; t0 += 64) {
            const int b = t0 + tid;
            const int c = (b < B) ? lcnt[b] : 0;
            int v = c;
#pragma unroll
            for (int o = 1; o < 64; o <<= 1) {
                const int u = __shfl_up(v, o, 64);
                if (tid >= o) v += u;
            }
            if (b < B) lpfx[b] = carry + v - c;
            carry += __shfl(v, 63, 64);
        }
    }
    __syncthreads();
    for (int b = tid; b < B; b += 256) {
        gb[b] = offs[(size_t)b * P_BLK + p] - lpfx[b];
        lcnt[b] = lpfx[b];                  // reuse as cursor
    }
    __syncthreads();

    for (int i = i0 + tid; i < iend; i += 256) {
        const int d = dst[i];
        const int b = d >> 8;
        const int slot = atomicAdd(&lcnt[b], 1);
        recs[slot] = make_int2((etype[i] * N + src[i]) | ((d & 255) << 20),
                               __float_as_int(A[i]));
        rbkt[slot] = (unsigned short)b;
    }
    __syncthreads();

    const int tot = iend - i0;
    for (int s = tid; s < tot; s += 256)
        packed[gb[rbkt[s]] + s] = recs[s];
}

// ---- single-pass per-bucket dst-sort using precomputed nodeOffs ----
__global__ __launch_bounds__(1024) void bucket_sort(
    const int2* __restrict__ packed, const int* __restrict__ offs,
    const int* __restrict__ nodeOffs, int2* __restrict__ sorted,
    int N, int B, int E)
{
    __shared__ int cur[BKT_NODES];
    const int bkt = blockIdx.x, tid = threadIdx.x;
    if (tid < BKT_NODES) {
        const int n = bkt * BKT_NODES + tid;
        cur[tid] = (n < N) ? nodeOffs[n] : E;
    }
    __syncthreads();
    const int beg = offs[(size_t)bkt * P_BLK];
    const int end = (bkt + 1 < B) ? offs[(size_t)(bkt + 1) * P_BLK] : E;
    for (int i = beg + tid; i < end; i += 1024) {
        const int2 rec = packed[i];
        const int dl = (rec.x >> 20) & (BKT_NODES - 1);
        const int pos = atomicAdd(&cur[dl], 1);
        sorted[pos] = rec;
    }
}

// ---- pull aggregation: one wave per dst node, register accumulation,
// 8 gathers in flight, no atomics. ----
__global__ __launch_bounds__(256) void dst_aggregate(
    const __half* __restrict__ XWh, const int* __restrict__ nodeOffs,
    const int2* __restrict__ sorted, float* __restrict__ Y, int N)
{
    const int lane = threadIdx.x & 63;
    const int hid  = lane >> 5;          // which edge of the pair
    const int fl   = lane & 31;          // feature-pair index
    const int wave = (int)((blockIdx.x * blockDim.x + threadIdx.x) >> 6);
    const int nWaves = (int)((gridDim.x * blockDim.x) >> 6);
    const __half2* XW2 = (const __half2*)XWh;

    for (int d = wave; d < N; d += nWaves) {
        const int beg = nodeOffs[d], end = nodeOffs[d + 1];
        float ax = 0.f, ay = 0.f;
        for (int base = beg; base < end; base += 64) {
            const int idx = base + lane;
            const int2 ka = (idx < end) ? sorted[idx] : make_int2(0, 0);  // a=0 -> no-op
            const int nb = min(64, end - base);
            const int npair = (nb + 1) >> 1;
            int s = 0;
            for (; s + 8 <= npair; s += 8) {
                int k[8], b[8];
#pragma unroll
                for (int u = 0; u < 8; ++u) {
                    const int j = 2 * (s + u) + hid;
                    k[u] = __shfl(ka.x, j, 64);
                    b[u] = __shfl(ka.y, j, 64);
                }
                __half2 v[8];
#pragma unroll
                for (int u = 0; u < 8; ++u)
                    v[u] = XW2[(size_t)(k[u] & 0xFFFFF) * 32 + fl];
#pragma unroll
                for (int u = 0; u < 8; ++u) {
                    const float2 f = __half22float2(v[u]);
                    const float a = __int_as_float(b[u]);
                    ax += a * f.x; ay += a * f.y;
                }
            }
            for (; s < npair; ++s) {
                const int j = 2 * s + hid;
                const int kk = __shfl(ka.x, j, 64);
                const int bb = __shfl(ka.y, j, 64);
                const __half2 v = XW2[(size_t)(kk & 0xFFFFF) * 32 + fl];
                const float2 f = __half22float2(v);
                const float a = __int_as_float(bb);
                ax += a * f.x; ay += a * f.y;
            }
        }
        ax += __shfl_xor(ax, 32, 64);    // combine even/odd edge halves
        ay += __shfl_xor(ay, 32, 64);
        if (lane < 32) {
            ((float2*)(Y + (size_t)d * FDIM))[fl] = make_float2(ax, ay);
        }
    }
}

extern "C" void kernel_launch(void* const* d_in, const int* in_sizes, int n_in,
                              void* d_out, int out_size, void* d_ws, size_t ws_size,
                              hipStream_t stream)
{
    const float* X     = (const float*)d_in[0];
    const float* Wmat  = (const float*)d_in[1];
    const float* A     = (const float*)d_in[2];
    const int*   src   = (const int*)d_in[3];
    const int*   dst   = (const int*)d_in[4];
    const int*   etype = (const int*)d_in[5];
    float* Y = (float*)d_out;

    const int N = in_sizes[0] / FDIM;            // 100000
    const int R = in_sizes[1] / (FDIM * FDIM);   // 8
    const int E = in_sizes[2];                   // 3200000
    (void)n_in; (void)out_size; (void)ws_size;

    const int B = (N + BKT_NODES - 1) / BKT_NODES;   // 391
    const int M = B * P_BLK;                         // bucket-scan length (~400k)
    const int chunk = (E + P_BLK - 1) / P_BLK;       // 3125 (<= CHUNK_CAP)
    const int CH  = (M + SB - 1) / SB;
    const int CH2 = (N + SB - 1) / SB;

    char* ws = (char*)d_ws;
    size_t off = 0;
    auto take = [&](size_t bytes) { char* p = ws + off; off = (off + bytes + 255) & ~(size_t)255; return p; };
    __half* XWh      = (__half*)take((size_t)R * N * FDIM * sizeof(__half)); // 102.4 MB
    int2*   packed   = (int2*)  take((size_t)E * sizeof(int2));              // 25.6 MB
    int2*   sorted   = (int2*)  take((size_t)E * sizeof(int2));              // 25.6 MB
    int*    cnt      = (int*)   take((size_t)M * sizeof(int));               // 1.6 MB
    int*    offs     = (int*)   take((size_t)(M + 1) * sizeof(int));         // 1.6 MB
    int*    nodeCnt  = (int*)   take((size_t)N * sizeof(int));               // 0.4 MB
    int*    nodeOffs = (int*)   take((size_t)(N + 1) * sizeof(int));         // 0.4 MB
    int*    bsums    = (int*)   take((size_t)SB * sizeof(int));
    int*    bsums2   = (int*)   take((size_t)SB * sizeof(int));

    hipMemsetAsync(nodeCnt, 0, (size_t)N * sizeof(int), stream);

    xw_gemm_mfma<<<(N + 255) / 256, 256, 0, stream>>>(X, Wmat, XWh, N, R);

    bin_hist<<<P_BLK, 256, 0, stream>>>(dst, cnt, nodeCnt, E, B, chunk);

    // scan chain 1: (bucket, block) offsets
    scan_partial<<<SB, 256, 0, stream>>>(cnt, bsums, M, CH);
    scan_block<<<1, 256, 0, stream>>>(bsums, SB);
    scan_final<<<SB, 64, 0, stream>>>(cnt, bsums, offs, M, CH, E);

    // scan chain 2: per-node offsets
    scan_partial<<<SB, 256, 0, stream>>>(nodeCnt, bsums2, N, CH2);
    scan_block<<<1, 256, 0, stream>>>(bsums2, SB);
    scan_final<<<SB, 64, 0, stream>>>(nodeCnt, bsums2, nodeOffs, N, CH2, E);

    bin_scatter<<<P_BLK, 256, 0, stream>>>(src, dst, etype, A, offs, packed, E, N, B, chunk);
    bucket_sort<<<B, 1024, 0, stream>>>(packed, offs, nodeOffs, sorted, N, B, E);

    dst_aggregate<<<2048, 256, 0, stream>>>(XWh, nodeOffs, sorted, Y, N);
}

// Round 10
// 314.953 us; speedup vs baseline: 1.3976x; 1.3976x over previous
//
#include <hip/hip_runtime.h>
#include <hip/hip_fp16.h>

#define FDIM 64
#define SB 200        // scan blocks
#define P_BLK 1024    // binning blocks
#define NB_MAX 400    // max dst buckets (ceil(100000/256)=391)
#define BKT_NODES 256 // nodes per dst bucket (dst >> 8)
#define CHUNK_CAP 3200 // LDS staging capacity (chunk = ceil(E/P_BLK) = 3125)

typedef __attribute__((ext_vector_type(8))) short short8;
typedef __attribute__((ext_vector_type(4))) float float4_;

__device__ __forceinline__ unsigned short f2bf(float x) {
    unsigned u = __float_as_uint(x);
    return (unsigned short)((u + 0x7FFF + ((u >> 16) & 1)) >> 16);   // RNE
}

// ---- MFMA GEMM: XWh[r][n][f] = fp16( X[n][:] @ W[r][:][f] ) ---- (unchanged)
__global__ __launch_bounds__(256) void xw_gemm_mfma(
    const float* __restrict__ X, const float* __restrict__ Wmat,
    __half* __restrict__ XWh, int N, int R)
{
    __shared__ unsigned short Wt[4 * 64 * 72];
    const int tid  = threadIdx.x;
    const int lane = tid & 63;
    const int wave = tid >> 6;
    const int quad = lane >> 4;
    const int l15  = lane & 15;
    const int blockBase = blockIdx.x * 256;

    short8 bfrag[4][2];
    bool tvalid[4];
#pragma unroll
    for (int t = 0; t < 4; ++t) {
        const int tb = blockBase + (wave * 4 + t) * 16;
        tvalid[t] = (tb < N);
        if (tvalid[t]) {
            const float* xp = X + (size_t)(tb + l15) * FDIM + quad * 8;
            const float4 x0 = *(const float4*)(xp);
            const float4 x1 = *(const float4*)(xp + 4);
            const float4 x2 = *(const float4*)(xp + 32);
            const float4 x3 = *(const float4*)(xp + 36);
            short8 b0, b1;
            b0[0]=f2bf(x0.x); b0[1]=f2bf(x0.y); b0[2]=f2bf(x0.z); b0[3]=f2bf(x0.w);
            b0[4]=f2bf(x1.x); b0[5]=f2bf(x1.y); b0[6]=f2bf(x1.z); b0[7]=f2bf(x1.w);
            b1[0]=f2bf(x2.x); b1[1]=f2bf(x2.y); b1[2]=f2bf(x2.z); b1[3]=f2bf(x2.w);
            b1[4]=f2bf(x3.x); b1[5]=f2bf(x3.y); b1[6]=f2bf(x3.z); b1[7]=f2bf(x3.w);
            bfrag[t][0] = b0; bfrag[t][1] = b1;
        } else {
            bfrag[t][0] = (short8)(0); bfrag[t][1] = (short8)(0);
        }
    }

    for (int rp = 0; rp < 2; ++rp) {
        __syncthreads();
#pragma unroll
        for (int it = 0; it < 16; ++it) {
            const int idx = it * 256 + tid;
            const int k  = idx & 63;
            const int f4 = (idx >> 6) & 15;
            const int r  = idx >> 10;
            const float4 w = *(const float4*)(Wmat + (((size_t)(rp * 4 + r) * FDIM + k) * FDIM + f4 * 4));
            const int base = (r * 64 + f4 * 4) * 72 + k;
            Wt[base + 0 * 72] = f2bf(w.x);
            Wt[base + 1 * 72] = f2bf(w.y);
            Wt[base + 2 * 72] = f2bf(w.z);
            Wt[base + 3 * 72] = f2bf(w.w);
        }
        __syncthreads();

#pragma unroll
        for (int t = 0; t < 4; ++t) {
            if (!tvalid[t]) continue;
            const int tb = blockBase + (wave * 4 + t) * 16;
            const int node = tb + l15;
#pragma unroll
            for (int r = 0; r < 4; ++r) {
                __half* orow = XWh + ((size_t)(rp * 4 + r) * N + node) * FDIM;
#pragma unroll
                for (int ft = 0; ft < 4; ++ft) {
                    const int f = ft * 16 + l15;
                    const unsigned short* wp = &Wt[(r * 64 + f) * 72 + quad * 8];
                    const short8 a0 = *(const short8*)(wp);
                    const short8 a1 = *(const short8*)(wp + 32);
                    float4_ acc = {0.f, 0.f, 0.f, 0.f};
                    acc = __builtin_amdgcn_mfma_f32_16x16x32_bf16(a0, bfrag[t][0], acc, 0, 0, 0);
                    acc = __builtin_amdgcn_mfma_f32_16x16x32_bf16(a1, bfrag[t][1], acc, 0, 0, 0);
                    const __half2 h01 = __floats2half2_rn(acc[0], acc[1]);
                    const __half2 h23 = __floats2half2_rn(acc[2], acc[3]);
                    uint2 st;
                    st.x = *(const unsigned*)&h01;
                    st.y = *(const unsigned*)&h23;
                    *(uint2*)(orow + ft * 16 + quad * 4) = st;
                }
            }
        }
    }
}

// ---- radix split by dst bucket (dst>>8): per-block LDS histogram only ----
__global__ __launch_bounds__(256) void bin_hist(
    const int* __restrict__ dst, int* __restrict__ cnt, int E, int B, int chunk)
{
    __shared__ int lh[NB_MAX];
    const int p = blockIdx.x, tid = threadIdx.x;
    for (int b = tid; b < B; b += 256) lh[b] = 0;
    __syncthreads();
    const int i0 = p * chunk, iend = min(i0 + chunk, E);
    for (int i = i0 + tid; i < iend; i += 256)
        atomicAdd(&lh[dst[i] >> 8], 1);
    __syncthreads();
    for (int b = tid; b < B; b += 256) cnt[(size_t)b * P_BLK + p] = lh[b];
}

// ---- hierarchical exclusive scan over M = B*P_BLK ints ----
__global__ __launch_bounds__(256) void scan_partial(
    const int* __restrict__ cnt, int* __restrict__ blockSums, int M, int CH)
{
    __shared__ int sh[256];
    const int b = blockIdx.x, tid = threadIdx.x;
    const int i0 = b * CH, iend = min(i0 + CH, M);
    int s = 0;
    for (int i = i0 + tid; i < iend; i += 256) s += cnt[i];
    sh[tid] = s; __syncthreads();
    for (int off = 128; off > 0; off >>= 1) {
        if (tid < off) sh[tid] += sh[tid + off];
        __syncthreads();
    }
    if (tid == 0) blockSums[b] = sh[0];
}

__global__ __launch_bounds__(256) void scan_block(int* blockSums, int nb)
{
    __shared__ int sh[256];
    const int tid = threadIdx.x;
    const int v = (tid < nb) ? blockSums[tid] : 0;
    sh[tid] = v; __syncthreads();
    for (int off = 1; off < 256; off <<= 1) {
        const int t = (tid >= off) ? sh[tid - off] : 0;
        __syncthreads();
        sh[tid] += t;
        __syncthreads();
    }
    if (tid < nb) blockSums[tid] = sh[tid] - v;   // exclusive
}

__global__ __launch_bounds__(64) void scan_final(
    const int* __restrict__ cnt, const int* __restrict__ blockSums,
    int* __restrict__ offs, int M, int CH, int E)
{
    const int b = blockIdx.x, lane = threadIdx.x;
    const int i0 = b * CH, iend = min(i0 + CH, M);
    int carry = blockSums[b];
    for (int t = i0; t < iend; t += 64) {
        const int i = t + lane;
        const int c = (i < iend) ? cnt[i] : 0;
        int v = c;
#pragma unroll
        for (int o = 1; o < 64; o <<= 1) {
            const int u = __shfl_up(v, o, 64);
            if (lane >= o) v += u;
        }
        if (i < iend) offs[i] = carry + v - c;
        carry += __shfl(v, 63, 64);
    }
    if (b == (int)gridDim.x - 1 && lane == 0) offs[M] = E;
}

// ---- LDS-staged scatter: counting-sort the block's chunk by bucket in LDS,
// then write bucket-ordered bursts (lines written ~once). ----
// record: lo = key(20b) | dstLow(8b)<<20 ; hi = A bits
__global__ __launch_bounds__(256) void bin_scatter(
    const int* __restrict__ src, const int* __restrict__ dst,
    const int* __restrict__ etype, const float* __restrict__ A,
    const int* __restrict__ offs, int2* __restrict__ packed,
    int E, int N, int B, int chunk)
{
    __shared__ int lcnt[NB_MAX];            // counts -> cursors
    __shared__ int lpfx[NB_MAX];            // in-chunk exclusive prefix
    __shared__ int gb[NB_MAX];              // global base - lpfx
    __shared__ int2 recs[CHUNK_CAP];        // 25.6 KB staged records
    __shared__ unsigned short rbkt[CHUNK_CAP]; // 6.4 KB bucket per slot
    const int p = blockIdx.x, tid = threadIdx.x;
    const int i0 = p * chunk, iend = min(i0 + chunk, E);

    for (int b = tid; b < B; b += 256) lcnt[b] = 0;
    __syncthreads();
    for (int i = i0 + tid; i < iend; i += 256)
        atomicAdd(&lcnt[dst[i] >> 8], 1);
    __syncthreads();

    // wave-0 exclusive prefix over B buckets
    if (tid < 64) {
        int carry = 0;
        for (int t0 = 0; t0 < B; t0 += 64) {
            const int b = t0 + tid;
            const int c = (b < B) ? lcnt[b] : 0;
            int v = c;
#pragma unroll
            for (int o = 1; o < 64; o <<= 1) {
                const int u = __shfl_up(v, o, 64);
                if (tid >= o) v += u;
            }
            if (b < B) lpfx[b] = carry + v - c;
            carry += __shfl(v, 63, 64);
        }
    }
    __syncthreads();
    for (int b = tid; b < B; b += 256) {
        gb[b] = offs[(size_t)b * P_BLK + p] - lpfx[b];
        lcnt[b] = lpfx[b];                  // reuse as cursor
    }
    __syncthreads();

    for (int i = i0 + tid; i < iend; i += 256) {
        const int d = dst[i];
        const int b = d >> 8;
        const int slot = atomicAdd(&lcnt[b], 1);
        recs[slot] = make_int2((etype[i] * N + src[i]) | ((d & 255) << 20),
                               __float_as_int(A[i]));
        rbkt[slot] = (unsigned short)b;
    }
    __syncthreads();

    const int tot = iend - i0;
    for (int s = tid; s < tot; s += 256)
        packed[gb[rbkt[s]] + s] = recs[s];
}

// ---- per-bucket dst-sort: counting sort on 8-bit dstLow within the bucket's
// contiguous segment (block-private lines). Emits per-node global offsets.
// 1024 threads (R8 ran 256: parallelism-starved). ----
__global__ __launch_bounds__(1024) void bucket_sort(
    const int2* __restrict__ packed, const int* __restrict__ offs,
    int2* __restrict__ sorted, int* __restrict__ nodeOffs, int N, int B, int E)
{
    __shared__ int hist[BKT_NODES];
    __shared__ int pfx[BKT_NODES + 1];
    __shared__ int cur[BKT_NODES];
    const int bkt = blockIdx.x, tid = threadIdx.x;
    const int beg = offs[(size_t)bkt * P_BLK];
    const int end = (bkt + 1 < B) ? offs[(size_t)(bkt + 1) * P_BLK] : E;

    if (tid < BKT_NODES) hist[tid] = 0;
    __syncthreads();
    for (int i = beg + tid; i < end; i += 1024)
        atomicAdd(&hist[(packed[i].x >> 20) & (BKT_NODES - 1)], 1);
    __syncthreads();
    if (tid == 0) {
        int s = 0;
        pfx[0] = 0;
        for (int i = 0; i < BKT_NODES; ++i) { s += hist[i]; pfx[i + 1] = s; }
    }
    __syncthreads();
    if (tid < BKT_NODES) {
        cur[tid] = pfx[tid];
        const int n = bkt * BKT_NODES + tid;
        if (n < N) nodeOffs[n] = beg + pfx[tid];
    }
    if (bkt == B - 1 && tid == 0) nodeOffs[N] = E;
    __syncthreads();
    for (int i = beg + tid; i < end; i += 1024) {
        const int2 rec = packed[i];
        const int dl = (rec.x >> 20) & (BKT_NODES - 1);
        const int pos = atomicAdd(&cur[dl], 1);
        sorted[beg + pos] = rec;
    }
}

// ---- pull aggregation: one wave per dst node, register accumulation,
// 8 gathers in flight, no atomics. ----
__global__ __launch_bounds__(256) void dst_aggregate(
    const __half* __restrict__ XWh, const int* __restrict__ nodeOffs,
    const int2* __restrict__ sorted, float* __restrict__ Y, int N)
{
    const int lane = threadIdx.x & 63;
    const int hid  = lane >> 5;          // which edge of the pair
    const int fl   = lane & 31;          // feature-pair index
    const int wave = (int)((blockIdx.x * blockDim.x + threadIdx.x) >> 6);
    const int nWaves = (int)((gridDim.x * blockDim.x) >> 6);
    const __half2* XW2 = (const __half2*)XWh;

    for (int d = wave; d < N; d += nWaves) {
        const int beg = nodeOffs[d], end = nodeOffs[d + 1];
        float ax = 0.f, ay = 0.f;
        for (int base = beg; base < end; base += 64) {
            const int idx = base + lane;
            const int2 ka = (idx < end) ? sorted[idx] : make_int2(0, 0);  // a=0 -> no-op
            const int nb = min(64, end - base);
            const int npair = (nb + 1) >> 1;
            int s = 0;
            for (; s + 8 <= npair; s += 8) {
                int k[8], b[8];
#pragma unroll
                for (int u = 0; u < 8; ++u) {
                    const int j = 2 * (s + u) + hid;
                    k[u] = __shfl(ka.x, j, 64);
                    b[u] = __shfl(ka.y, j, 64);
                }
                __half2 v[8];
#pragma unroll
                for (int u = 0; u < 8; ++u)
                    v[u] = XW2[(size_t)(k[u] & 0xFFFFF) * 32 + fl];
#pragma unroll
                for (int u = 0; u < 8; ++u) {
                    const float2 f = __half22float2(v[u]);
                    const float a = __int_as_float(b[u]);
                    ax += a * f.x; ay += a * f.y;
                }
            }
            for (; s < npair; ++s) {
                const int j = 2 * s + hid;
                const int kk = __shfl(ka.x, j, 64);
                const int bb = __shfl(ka.y, j, 64);
                const __half2 v = XW2[(size_t)(kk & 0xFFFFF) * 32 + fl];
                const float2 f = __half22float2(v);
                const float a = __int_as_float(bb);
                ax += a * f.x; ay += a * f.y;
            }
        }
        ax += __shfl_xor(ax, 32, 64);    // combine even/odd edge halves
        ay += __shfl_xor(ay, 32, 64);
        if (lane < 32) {
            ((float2*)(Y + (size_t)d * FDIM))[fl] = make_float2(ax, ay);
        }
    }
}

extern "C" void kernel_launch(void* const* d_in, const int* in_sizes, int n_in,
                              void* d_out, int out_size, void* d_ws, size_t ws_size,
                              hipStream_t stream)
{
    const float* X     = (const float*)d_in[0];
    const float* Wmat  = (const float*)d_in[1];
    const float* A     = (const float*)d_in[2];
    const int*   src   = (const int*)d_in[3];
    const int*   dst   = (const int*)d_in[4];
    const int*   etype = (const int*)d_in[5];
    float* Y = (float*)d_out;

    const int N = in_sizes[0] / FDIM;            // 100000
    const int R = in_sizes[1] / (FDIM * FDIM);   // 8
    const int E = in_sizes[2];                   // 3200000
    (void)n_in; (void)out_size; (void)ws_size;

    const int B = (N + BKT_NODES - 1) / BKT_NODES;   // 391
    const int M = B * P_BLK;                         // scan length (~400k)
    const int chunk = (E + P_BLK - 1) / P_BLK;       // 3125 (<= CHUNK_CAP)
    const int CH = (M + SB - 1) / SB;

    char* ws = (char*)d_ws;
    size_t off = 0;
    auto take = [&](size_t bytes) { char* p = ws + off; off = (off + bytes + 255) & ~(size_t)255; return p; };
    __half* XWh      = (__half*)take((size_t)R * N * FDIM * sizeof(__half)); // 102.4 MB
    int2*   packed   = (int2*)  take((size_t)E * sizeof(int2));              // 25.6 MB
    int2*   sorted   = (int2*)  take((size_t)E * sizeof(int2));              // 25.6 MB
    int*    cnt      = (int*)   take((size_t)M * sizeof(int));               // 1.6 MB
    int*    offs     = (int*)   take((size_t)(M + 1) * sizeof(int));         // 1.6 MB
    int*    nodeOffs = (int*)   take((size_t)(N + 1) * sizeof(int));         // 0.4 MB
    int*    bsums    = (int*)   take((size_t)SB * sizeof(int));

    xw_gemm_mfma<<<(N + 255) / 256, 256, 0, stream>>>(X, Wmat, XWh, N, R);

    bin_hist<<<P_BLK, 256, 0, stream>>>(dst, cnt, E, B, chunk);
    scan_partial<<<SB, 256, 0, stream>>>(cnt, bsums, M, CH);
    scan_block<<<1, 256, 0, stream>>>(bsums, SB);
    scan_final<<<SB, 64, 0, stream>>>(cnt, bsums, offs, M, CH, E);
    bin_scatter<<<P_BLK, 256, 0, stream>>>(src, dst, etype, A, offs, packed, E, N, B, chunk);
    bucket_sort<<<B, 1024, 0, stream>>>(packed, offs, sorted, nodeOffs, N, B, E);

    dst_aggregate<<<2048, 256, 0, stream>>>(XWh, nodeOffs, sorted, Y, N);
}